// Round 12
// baseline (818.529 us; speedup 1.0000x reference)
//
#include <hip/hip_runtime.h>
#include <math.h>

#define B_   8
#define T_   256
#define U_   64
#define UP1  65
#define DE   640
#define J_   512
#define V_   1024
#define NCELL (B_ * T_ * UP1)
#define LOG0 -1e30f

typedef __attribute__((ext_vector_type(4))) float f32x4;
typedef __attribute__((ext_vector_type(8))) int   i32x8;
typedef __attribute__((address_space(3))) unsigned char lds_uc;
typedef const __attribute__((address_space(1))) unsigned char glb_uc;

// ---------------- DPP wave64 scan/reduce helpers -------------------------------------
template<int CTRL, int RM>
__device__ __forceinline__ float dppz(float x) {
    return __builtin_bit_cast(float,
        __builtin_amdgcn_update_dpp(0, __builtin_bit_cast(int, x), CTRL, RM, 0xf, false));
}
template<int CTRL, int RM>
__device__ __forceinline__ float dpps(float x) {
    int xi = __builtin_bit_cast(int, x);
    return __builtin_bit_cast(float,
        __builtin_amdgcn_update_dpp(xi, xi, CTRL, RM, 0xf, false));
}
__device__ __forceinline__ float wave_prefix_sum(float v) {
    v += dppz<0x111, 0xf>(v);
    v += dppz<0x112, 0xf>(v);
    v += dppz<0x114, 0xf>(v);
    v += dppz<0x118, 0xf>(v);
    v += dppz<0x142, 0xa>(v);
    v += dppz<0x143, 0xc>(v);
    return v;
}
__device__ __forceinline__ float wave_max_all(float v) {
    v = fmaxf(v, dpps<0x111, 0xf>(v));
    v = fmaxf(v, dpps<0x112, 0xf>(v));
    v = fmaxf(v, dpps<0x114, 0xf>(v));
    v = fmaxf(v, dpps<0x118, 0xf>(v));
    v = fmaxf(v, dpps<0x142, 0xa>(v));
    v = fmaxf(v, dpps<0x143, 0xc>(v));
    return __builtin_bit_cast(float,
        __builtin_amdgcn_readlane(__builtin_bit_cast(int, v), 63));
}
__device__ __forceinline__ float rdlane(float v, int l) {
    return __builtin_bit_cast(float,
        __builtin_amdgcn_readlane(__builtin_bit_cast(int, v), l));
}

// LDS swizzle for fp8 hB: row m (512B rows), cb = column byte offset (8B granular).
__device__ __forceinline__ unsigned hb8(unsigned m, unsigned cb) {
    return m * 512u + (cb ^ ((m & 15u) << 3));
}

// ---------------- Kernel A: C[M x 512] = A[M x 640] * W[640 x 512] (+bias) -------------
__global__ __launch_bounds__(256) void gemm_in(const float* __restrict__ A,
                                               const float* __restrict__ W,
                                               const float* __restrict__ bias,
                                               float* __restrict__ C, int M) {
    __shared__ float As[16][64];
    __shared__ float Bs[16][64];
    int tid  = threadIdx.x;
    int row0 = blockIdx.x * 64;
    int col0 = blockIdx.y * 64;
    int tx = tid & 15, ty = tid >> 4;
    float acc[4][4] = {};
    int ar  = tid >> 2;
    int akq = tid & 3;
    int bkr = tid >> 4;
    int bcq = tid & 15;
    for (int k0 = 0; k0 < DE; k0 += 16) {
        float4 av = make_float4(0.f, 0.f, 0.f, 0.f);
        int arow = row0 + ar;
        if (arow < M) av = *(const float4*)&A[arow * DE + k0 + akq * 4];
        As[akq * 4 + 0][ar] = av.x;
        As[akq * 4 + 1][ar] = av.y;
        As[akq * 4 + 2][ar] = av.z;
        As[akq * 4 + 3][ar] = av.w;
        *(float4*)&Bs[bkr][bcq * 4] = *(const float4*)&W[(k0 + bkr) * J_ + col0 + bcq * 4];
        __syncthreads();
#pragma unroll
        for (int k = 0; k < 16; ++k) {
            float4 a4 = *(const float4*)&As[k][ty * 4];
            float4 b4 = *(const float4*)&Bs[k][tx * 4];
            float a[4] = {a4.x, a4.y, a4.z, a4.w};
            float b[4] = {b4.x, b4.y, b4.z, b4.w};
#pragma unroll
            for (int i = 0; i < 4; ++i)
#pragma unroll
                for (int j = 0; j < 4; ++j) acc[i][j] += a[i] * b[j];
        }
        __syncthreads();
    }
#pragma unroll
    for (int i = 0; i < 4; ++i) {
        int row = row0 + ty * 4 + i;
        if (row >= M) continue;
#pragma unroll
        for (int j = 0; j < 4; ++j) {
            int col = col0 + tx * 4 + j;
            float v = acc[i][j];
            if (bias) v += bias[col];
            C[row * J_ + col] = v;
        }
    }
}

// ---- Kernel W: W_out[512][1024] -> K128-frag-major fp8(e4m3) Wf (round-8 layout) ----
// byte = tl*8192 + s(=k>>7)*2048 + ((k>>4)&1)*1024 + (lg*16+ln)*16 + (k&15),
// ln=col&15, lg=(k>>5)&3. Wave B-frag = two coalesced int4 loads (+0, +1024).
__global__ __launch_bounds__(256) void wt_kernel(const float* __restrict__ W,
                                                 unsigned char* __restrict__ Wf) {
    __shared__ float tile[32][33];
    int tid = threadIdx.x;
    int tx = tid & 31, ty = tid >> 5;  // 32x8
    int v0 = blockIdx.x * 32, k0 = blockIdx.y * 32;
#pragma unroll
    for (int i = 0; i < 4; ++i)
        tile[ty + i * 8][tx] = W[(size_t)(k0 + ty + i * 8) * V_ + v0 + tx];
    __syncthreads();
    if (tid < 128) {
        int vl = tid >> 2, q = tid & 3;
        int v  = v0 + vl;
        float x[8];
#pragma unroll
        for (int j = 0; j < 8; ++j) x[j] = tile[q * 8 + j][vl];
        int lo = 0, hi = 0;
        lo = __builtin_amdgcn_cvt_pk_fp8_f32(x[0], x[1], lo, false);
        lo = __builtin_amdgcn_cvt_pk_fp8_f32(x[2], x[3], lo, true);
        hi = __builtin_amdgcn_cvt_pk_fp8_f32(x[4], x[5], hi, false);
        hi = __builtin_amdgcn_cvt_pk_fp8_f32(x[6], x[7], hi, true);
        int tl = v >> 4, ln = v & 15;
        int s  = k0 >> 7, lg = (k0 >> 5) & 3;
        *(int2*)(Wf + tl * 8192 + s * 2048 + (q >> 1) * 1024 + (lg * 16 + ln) * 16 +
                 (q & 1) * 8) = make_int2(lo, hi);
    }
}

// ---- Kernel H: h = tanh(ep+pp) fp8, pre-swizzled, OUTPUT-LINEAR (coalesced writes) ---
__global__ __launch_bounds__(512) void hgen_kernel(const float* __restrict__ ep,
                                                   const float* __restrict__ pp,
                                                   unsigned char* __restrict__ hG) {
    int tid  = threadIdx.x;
    int tile = blockIdx.x;
    unsigned char* outb = hG + (size_t)tile * 32768;
#pragma unroll
    for (int i = 0; i < 4; ++i) {
        int g   = tid + i * 512;
        int row = g >> 5;
        int lin9 = (g & 31) * 16;
        unsigned swz = ((unsigned)(row & 15)) << 3;
        int k0   = lin9 ^ (int)(swz & ~8u);
        int swap = row & 1;
        int cell = tile * 64 + row;
        unsigned epRow = (unsigned)cell / 65u;
        int u = cell - (int)epRow * 65;
        int b = (int)(epRow >> 8);
        const float* epr = ep + (size_t)epRow * J_ + k0;
        const float* ppr = pp + (size_t)(b * UP1 + u) * J_ + k0;
        float t[16];
#pragma unroll
        for (int q = 0; q < 4; ++q) {
            float4 e = *(const float4*)(epr + q * 4);
            float4 p = *(const float4*)(ppr + q * 4);
            float xs[4] = {e.x + p.x, e.y + p.y, e.z + p.z, e.w + p.w};
#pragma unroll
            for (int j = 0; j < 4; ++j) {
                float e2 = __expf(2.f * xs[j]);
                t[q * 4 + j] = 1.f - 2.f / (e2 + 1.f);
            }
        }
        int a0 = 0, a1 = 0, b0 = 0, b1 = 0;
        a0 = __builtin_amdgcn_cvt_pk_fp8_f32(t[0], t[1], a0, false);
        a0 = __builtin_amdgcn_cvt_pk_fp8_f32(t[2], t[3], a0, true);
        a1 = __builtin_amdgcn_cvt_pk_fp8_f32(t[4], t[5], a1, false);
        a1 = __builtin_amdgcn_cvt_pk_fp8_f32(t[6], t[7], a1, true);
        b0 = __builtin_amdgcn_cvt_pk_fp8_f32(t[8], t[9], b0, false);
        b0 = __builtin_amdgcn_cvt_pk_fp8_f32(t[10], t[11], b0, true);
        b1 = __builtin_amdgcn_cvt_pk_fp8_f32(t[12], t[13], b1, false);
        b1 = __builtin_amdgcn_cvt_pk_fp8_f32(t[14], t[15], b1, true);
        int4 w = swap ? make_int4(b0, b1, a0, a1) : make_int4(a0, a1, b0, b1);
        *(int4*)(outb + g * 16) = w;
    }
}

// ---- Kernel B: MX-fp8 K=128 joint, 4-way col-split, gll staging, XCD-grouped --------
// bx -> tile t=(bx>>5)*8+(bx&7), quarter q=(bx>>3)&3: same-tile quarters share bx%8
// (same XCD L2) and are temporally adjacent. Wave wc: cols q*256 + wc*64.
__global__ __launch_bounds__(256, 3) void joint_mfma(const unsigned char* __restrict__ hG,
                                                     const unsigned char* __restrict__ Wf,
                                                     const float* __restrict__ bout,
                                                     const int* __restrict__ labels,
                                                     const int* __restrict__ pblank,
                                                     float* __restrict__ Spart,
                                                     float* __restrict__ blp,
                                                     float* __restrict__ llp) {
    __shared__ __align__(16) unsigned char hB[64 * 512];
    __shared__ float ps[4][64];

    int tid  = threadIdx.x;
    int bx   = blockIdx.x;
    int tile = (bx >> 5) * 8 + (bx & 7);
    int bh   = (bx >> 3) & 3;
    int c0   = tile * 64;
    int wc = tid >> 6, lane = tid & 63;
    int lg = lane >> 4, ln = lane & 15;

    // ---- stage hG tile -> LDS via global_load_lds (linear dest, 1KB/issue/wave) ----
    {
        const unsigned char* gsrc = hG + (size_t)tile * 32768 + wc * 8192 + lane * 16;
#pragma unroll
        for (int i = 0; i < 8; ++i)
            __builtin_amdgcn_global_load_lds((glb_uc*)(gsrc + i * 1024),
                                             (lds_uc*)(hB + wc * 8192 + i * 1024),
                                             16, 0, 0);
    }

    // B-frag base: tiles (bh*16 + wc*4 + ni); two int4 per frag at +0/+1024
    const unsigned char* wfB = Wf + (size_t)((bh << 4) + (wc << 2)) * 8192 + lane * 16;

    union BF { int4 q[2]; i32x8 v; };
    union AF { long l[4]; i32x8 v; };
    BF bf[4];
    AF af[4];

    __syncthreads();   // drains global_load_lds (vmcnt) + all waves staged

    f32x4 acc[4][4] = {};

#pragma unroll
    for (int s = 0; s < 4; ++s) {
        // A-frags: 4 x (4 x 8B swizzled LDS reads), 32 consecutive k per lane
#pragma unroll
        for (int mi = 0; mi < 4; ++mi) {
            unsigned m  = (unsigned)(mi * 16 + ln);
            unsigned cb = (unsigned)(s * 128 + lg * 32);
            af[mi].l[0] = *(const long*)(hB + hb8(m, cb));
            af[mi].l[1] = *(const long*)(hB + hb8(m, cb + 8));
            af[mi].l[2] = *(const long*)(hB + hb8(m, cb + 16));
            af[mi].l[3] = *(const long*)(hB + hb8(m, cb + 24));
        }
        // B-frags for this s
#pragma unroll
        for (int ni = 0; ni < 4; ++ni) {
            const unsigned char* p = wfB + ni * 8192 + s * 2048;
            bf[ni].q[0] = *(const int4*)p;
            bf[ni].q[1] = *(const int4*)(p + 1024);
        }
        __builtin_amdgcn_s_setprio(1);
#pragma unroll
        for (int mi = 0; mi < 4; ++mi)
#pragma unroll
            for (int ni = 0; ni < 4; ++ni)
                acc[mi][ni] = __builtin_amdgcn_mfma_scale_f32_16x16x128_f8f6f4(
                    af[mi].v, bf[ni].v, acc[mi][ni], 0, 0, 0, 0x7F7F7F7F, 0, 0x7F7F7F7F);
        __builtin_amdgcn_s_setprio(0);
    }

    // ---- epilogue: bias, partial exp-sum over this quarter's 256 cols, raw gather ----
    float bo[4];
#pragma unroll
    for (int ni = 0; ni < 4; ++ni) bo[ni] = bout[(bh << 8) + (wc << 6) + (ni << 4) + ln];
#pragma unroll
    for (int mi = 0; mi < 4; ++mi)
#pragma unroll
        for (int ni = 0; ni < 4; ++ni)
#pragma unroll
            for (int r = 0; r < 4; ++r) acc[mi][ni][r] += bo[ni];

#pragma unroll
    for (int mi = 0; mi < 4; ++mi) {
#pragma unroll
        for (int r = 0; r < 4; ++r) {
            float s = 0.f;
#pragma unroll
            for (int ni = 0; ni < 4; ++ni) s += __expf(acc[mi][ni][r]);
            s += __shfl_xor(s, 1);
            s += __shfl_xor(s, 2);
            s += __shfl_xor(s, 4);
            s += __shfl_xor(s, 8);
            if (ln == 0) ps[wc][mi * 16 + lg * 4 + r] = s;
        }
    }
    __syncthreads();
    if (tid < 64) {
        float S = ps[0][tid] + ps[1][tid] + ps[2][tid] + ps[3][tid];
        Spart[(size_t)bh * NCELL + c0 + tid] = S;
    }

    int blank = *pblank;
#pragma unroll
    for (int mi = 0; mi < 4; ++mi) {
#pragma unroll
        for (int r = 0; r < 4; ++r) {
            int row  = mi * 16 + lg * 4 + r;
            int cell = c0 + row;
            unsigned epRow = (unsigned)cell / 65u;
            int u = cell - (int)epRow * 65;
            int b = (int)(epRow >> 8);
            int lab = (u < U_) ? labels[(b << 6) + u] : -1;
#pragma unroll
            for (int ni = 0; ni < 4; ++ni) {
                int col = (bh << 8) + (wc << 6) + (ni << 4) + ln;
                float lgt = acc[mi][ni][r];
                if (col == blank) blp[cell] = lgt;                            // raw
                if (col == lab)   llp[(size_t)(((int)epRow << 6) + u)] = lgt; // raw
            }
        }
    }
}

// ---- Pass 2: lse = log(S0+S1+S2+S3); subtract from raw blank/label logits ----
__global__ __launch_bounds__(256) void pass2_kernel(const float* __restrict__ Spart,
                                                    float* __restrict__ blp,
                                                    float* __restrict__ llp) {
    int idx = blockIdx.x * 256 + threadIdx.x;
    if (idx >= NCELL) return;
    float lse = __logf(Spart[idx] + Spart[NCELL + idx] +
                       Spart[2 * NCELL + idx] + Spart[3 * NCELL + idx]);
    blp[idx] -= lse;
    unsigned epRow = (unsigned)idx / 65u;
    int u = idx - (int)epRow * 65;
    if (u < U_) llp[(size_t)((epRow << 6) + u)] -= lse;
}

// ------- Kernel C: alpha scan, log2-domain, DPP scans + prefetched loads ---------------
__global__ __launch_bounds__(512) void scan_kernel(const float* __restrict__ blp,
                                                   const float* __restrict__ llp,
                                                   const int* __restrict__ enc_lens,
                                                   const int* __restrict__ label_lens,
                                                   float* __restrict__ out) {
    __shared__ float lossArr[B_];
    const float K2  = 1.4426950408889634f;
    const float LN2 = 0.6931471805599453f;
    int tid  = threadIdx.x;
    int b    = tid >> 6;
    int lane = tid & 63;
    int el = enc_lens[b];
    int ll = label_lens[b];
    float alpha   = (lane == 0) ? 0.f : LOG0;
    float alpha64 = LOG0;
    const float* bb = &blp[(size_t)b * T_ * UP1];
    const float* lb = &llp[(size_t)b * T_ * U_];

    float bv_n   = bb[lane] * K2;
    float bv64_n = bb[64] * K2;
    float lv_n   = lb[lane] * K2;

    for (int t = 0; t < T_; ++t) {
        float bv = bv_n, bv64 = bv64_n, lv = lv_n;
        if (t + 1 < T_) {
            bv_n   = bb[(t + 1) * UP1 + lane] * K2;
            bv64_n = bb[(t + 1) * UP1 + 64] * K2;
            lv_n   = lb[(t + 1) * U_ + lane] * K2;
        }
        float P = wave_prefix_sum(lv);
        float L = dpps<0x111, 0xf>(P);
        float P15 = rdlane(P, 15), P31 = rdlane(P, 31), P47 = rdlane(P, 47);
        if (lane == 0)  L = 0.f;
        if (lane == 16) L = P15;
        if (lane == 32) L = P31;
        if (lane == 48) L = P47;
        float P63 = rdlane(P, 63);
        float x   = alpha + bv - L;
        float x64 = alpha64 + bv64 - P63;
        float M = fmaxf(wave_max_all(x), x64);
        float S = wave_prefix_sum(__builtin_amdgcn_exp2f(x - M));
        float S63 = rdlane(S, 63);
        float anew   = L + M + __builtin_amdgcn_logf(S);
        float anew64 = P63 + M +
                       __builtin_amdgcn_logf(S63 + __builtin_amdgcn_exp2f(x64 - M));
        if (t < el) {
            alpha   = anew;
            alpha64 = anew64;
        }
    }

    float term = bb[(el - 1) * UP1 + ll] * K2;
    int li = (ll < 64) ? ll : 63;
    float aU = __shfl(alpha, li);
    if (ll >= 64) aU = alpha64;
    if (lane == 0) lossArr[b] = -(aU + term) * LN2;
    __syncthreads();
    if (tid == 0) {
        float s = 0.f;
        for (int i = 0; i < B_; ++i) s += lossArr[i];
        out[0] = s / (float)B_;
    }
}

extern "C" void kernel_launch(void* const* d_in, const int* in_sizes, int n_in,
                              void* d_out, int out_size, void* d_ws, size_t ws_size,
                              hipStream_t stream) {
    (void)in_sizes; (void)n_in; (void)out_size; (void)ws_size;
    const float* enc        = (const float*)d_in[0];
    const float* pred       = (const float*)d_in[1];
    const float* W_enc      = (const float*)d_in[2];
    const float* W_pred     = (const float*)d_in[3];
    const float* b_joint    = (const float*)d_in[4];
    const float* W_out      = (const float*)d_in[5];
    const float* b_out      = (const float*)d_in[6];
    const int*   labels     = (const int*)d_in[7];
    const int*   enc_lens   = (const int*)d_in[8];
    const int*   label_lens = (const int*)d_in[9];
    const int*   blank_id   = (const int*)d_in[10];

    float* ep  = (float*)d_ws;                      // B*T*J   = 1,048,576 f
    float* pp  = ep  + (size_t)B_ * T_ * J_;        // B*65*J  =   266,240 f
    float* blp = pp  + (size_t)B_ * UP1 * J_;       // B*T*65  =   133,120 f
    float* llp = blp + (size_t)B_ * T_ * UP1;       // B*T*64  =   131,072 f
    unsigned char* Wf = (unsigned char*)(llp + (size_t)B_ * T_ * U_);  // 512KB frag fp8
    float* Spart = (float*)(Wf + (size_t)V_ * J_);  // 4 * NCELL f32
    unsigned char* hG = (unsigned char*)(Spart + (size_t)4 * NCELL);   // NCELL*512 fp8

    wt_kernel<<<dim3(V_ / 32, J_ / 32), dim3(256), 0, stream>>>(W_out, Wf);
    gemm_in<<<dim3((B_ * T_ + 63) / 64, J_ / 64), dim3(256), 0, stream>>>(
        enc, W_enc, b_joint, ep, B_ * T_);
    gemm_in<<<dim3((B_ * UP1 + 63) / 64, J_ / 64), dim3(256), 0, stream>>>(
        pred, W_pred, nullptr, pp, B_ * UP1);
    hgen_kernel<<<dim3(NCELL / 64), dim3(512), 0, stream>>>(ep, pp, hG);
    joint_mfma<<<dim3(NCELL / 64 * 4), dim3(256), 0, stream>>>(
        hG, Wf, b_out, labels, blank_id, Spart, blp, llp);
    pass2_kernel<<<dim3((NCELL + 255) / 256), dim3(256), 0, stream>>>(Spart, blp, llp);
    scan_kernel<<<dim3(1), dim3(512), 0, stream>>>(blp, llp, enc_lens, label_lens,
                                                   (float*)d_out);
}

// Round 13
// 360.040 us; speedup vs baseline: 2.2734x; 2.2734x over previous
//
#include <hip/hip_runtime.h>
#include <math.h>

#define B_   8
#define T_   256
#define U_   64
#define UP1  65
#define DE   640
#define J_   512
#define V_   1024
#define NCELL (B_ * T_ * UP1)
#define LOG0 -1e30f

typedef __attribute__((ext_vector_type(4))) float f32x4;
typedef __attribute__((address_space(3))) unsigned char lds_uc;
typedef const __attribute__((address_space(1))) unsigned char glb_uc;

// ---------------- DPP wave64 scan/reduce helpers -------------------------------------
template<int CTRL, int RM>
__device__ __forceinline__ float dppz(float x) {
    return __builtin_bit_cast(float,
        __builtin_amdgcn_update_dpp(0, __builtin_bit_cast(int, x), CTRL, RM, 0xf, false));
}
template<int CTRL, int RM>
__device__ __forceinline__ float dpps(float x) {
    int xi = __builtin_bit_cast(int, x);
    return __builtin_bit_cast(float,
        __builtin_amdgcn_update_dpp(xi, xi, CTRL, RM, 0xf, false));
}
__device__ __forceinline__ float wave_prefix_sum(float v) {
    v += dppz<0x111, 0xf>(v);
    v += dppz<0x112, 0xf>(v);
    v += dppz<0x114, 0xf>(v);
    v += dppz<0x118, 0xf>(v);
    v += dppz<0x142, 0xa>(v);
    v += dppz<0x143, 0xc>(v);
    return v;
}
__device__ __forceinline__ float wave_max_all(float v) {
    v = fmaxf(v, dpps<0x111, 0xf>(v));
    v = fmaxf(v, dpps<0x112, 0xf>(v));
    v = fmaxf(v, dpps<0x114, 0xf>(v));
    v = fmaxf(v, dpps<0x118, 0xf>(v));
    v = fmaxf(v, dpps<0x142, 0xa>(v));
    v = fmaxf(v, dpps<0x143, 0xc>(v));
    return __builtin_bit_cast(float,
        __builtin_amdgcn_readlane(__builtin_bit_cast(int, v), 63));
}
__device__ __forceinline__ float rdlane(float v, int l) {
    return __builtin_bit_cast(float,
        __builtin_amdgcn_readlane(__builtin_bit_cast(int, v), l));
}

// LDS swizzle for fp8 hB: row m (512B rows), cb = column byte offset (8B granular).
__device__ __forceinline__ unsigned hb8(unsigned m, unsigned cb) {
    return m * 512u + (cb ^ ((m & 15u) << 3));
}

// ---------------- Kernel A: C[M x 512] = A[M x 640] * W[640 x 512] (+bias) -------------
__global__ __launch_bounds__(256) void gemm_in(const float* __restrict__ A,
                                               const float* __restrict__ W,
                                               const float* __restrict__ bias,
                                               float* __restrict__ C, int M) {
    __shared__ float As[16][64];
    __shared__ float Bs[16][64];
    int tid  = threadIdx.x;
    int row0 = blockIdx.x * 64;
    int col0 = blockIdx.y * 64;
    int tx = tid & 15, ty = tid >> 4;
    float acc[4][4] = {};
    int ar  = tid >> 2;
    int akq = tid & 3;
    int bkr = tid >> 4;
    int bcq = tid & 15;
    for (int k0 = 0; k0 < DE; k0 += 16) {
        float4 av = make_float4(0.f, 0.f, 0.f, 0.f);
        int arow = row0 + ar;
        if (arow < M) av = *(const float4*)&A[arow * DE + k0 + akq * 4];
        As[akq * 4 + 0][ar] = av.x;
        As[akq * 4 + 1][ar] = av.y;
        As[akq * 4 + 2][ar] = av.z;
        As[akq * 4 + 3][ar] = av.w;
        *(float4*)&Bs[bkr][bcq * 4] = *(const float4*)&W[(k0 + bkr) * J_ + col0 + bcq * 4];
        __syncthreads();
#pragma unroll
        for (int k = 0; k < 16; ++k) {
            float4 a4 = *(const float4*)&As[k][ty * 4];
            float4 b4 = *(const float4*)&Bs[k][tx * 4];
            float a[4] = {a4.x, a4.y, a4.z, a4.w};
            float b[4] = {b4.x, b4.y, b4.z, b4.w};
#pragma unroll
            for (int i = 0; i < 4; ++i)
#pragma unroll
                for (int j = 0; j < 4; ++j) acc[i][j] += a[i] * b[j];
        }
        __syncthreads();
    }
#pragma unroll
    for (int i = 0; i < 4; ++i) {
        int row = row0 + ty * 4 + i;
        if (row >= M) continue;
#pragma unroll
        for (int j = 0; j < 4; ++j) {
            int col = col0 + tx * 4 + j;
            float v = acc[i][j];
            if (bias) v += bias[col];
            C[row * J_ + col] = v;
        }
    }
}

// ---- Kernel W: W_out[512][1024] -> fragment-major fp8(e4m3) Wf (round-6 K32 layout) --
__global__ __launch_bounds__(256) void wt_kernel(const float* __restrict__ W,
                                                 unsigned char* __restrict__ Wf) {
    __shared__ float tile[32][33];
    int tid = threadIdx.x;
    int tx = tid & 31, ty = tid >> 5;  // 32x8
    int v0 = blockIdx.x * 32, k0 = blockIdx.y * 32;
#pragma unroll
    for (int i = 0; i < 4; ++i)
        tile[ty + i * 8][tx] = W[(size_t)(k0 + ty + i * 8) * V_ + v0 + tx];
    __syncthreads();
    if (tid < 128) {
        int vl = tid >> 2, lg = tid & 3;
        int v  = v0 + vl;
        float x[8];
#pragma unroll
        for (int j = 0; j < 8; ++j) x[j] = tile[lg * 8 + j][vl];
        int lo = 0, hi = 0;
        lo = __builtin_amdgcn_cvt_pk_fp8_f32(x[0], x[1], lo, false);
        lo = __builtin_amdgcn_cvt_pk_fp8_f32(x[2], x[3], lo, true);
        hi = __builtin_amdgcn_cvt_pk_fp8_f32(x[4], x[5], hi, false);
        hi = __builtin_amdgcn_cvt_pk_fp8_f32(x[6], x[7], hi, true);
        int tl = v >> 4, ln = v & 15, kt = k0 >> 5;
        *(int2*)(Wf + tl * 8192 + kt * 512 + (lg * 16 + ln) * 8) = make_int2(lo, hi);
    }
}

// ---- Kernel H: h = tanh(ep+pp) fp8, pre-swizzled, OUTPUT-LINEAR (coalesced writes) ---
__global__ __launch_bounds__(512) void hgen_kernel(const float* __restrict__ ep,
                                                   const float* __restrict__ pp,
                                                   unsigned char* __restrict__ hG) {
    int tid  = threadIdx.x;
    int tile = blockIdx.x;
    unsigned char* outb = hG + (size_t)tile * 32768;
#pragma unroll
    for (int i = 0; i < 4; ++i) {
        int g   = tid + i * 512;
        int row = g >> 5;
        int lin9 = (g & 31) * 16;
        unsigned swz = ((unsigned)(row & 15)) << 3;
        int k0   = lin9 ^ (int)(swz & ~8u);
        int swap = row & 1;
        int cell = tile * 64 + row;
        unsigned epRow = (unsigned)cell / 65u;
        int u = cell - (int)epRow * 65;
        int b = (int)(epRow >> 8);
        const float* epr = ep + (size_t)epRow * J_ + k0;
        const float* ppr = pp + (size_t)(b * UP1 + u) * J_ + k0;
        float t[16];
#pragma unroll
        for (int q = 0; q < 4; ++q) {
            float4 e = *(const float4*)(epr + q * 4);
            float4 p = *(const float4*)(ppr + q * 4);
            float xs[4] = {e.x + p.x, e.y + p.y, e.z + p.z, e.w + p.w};
#pragma unroll
            for (int j = 0; j < 4; ++j) {
                float e2 = __expf(2.f * xs[j]);
                t[q * 4 + j] = 1.f - 2.f / (e2 + 1.f);
            }
        }
        int a0 = 0, a1 = 0, b0 = 0, b1 = 0;
        a0 = __builtin_amdgcn_cvt_pk_fp8_f32(t[0], t[1], a0, false);
        a0 = __builtin_amdgcn_cvt_pk_fp8_f32(t[2], t[3], a0, true);
        a1 = __builtin_amdgcn_cvt_pk_fp8_f32(t[4], t[5], a1, false);
        a1 = __builtin_amdgcn_cvt_pk_fp8_f32(t[6], t[7], a1, true);
        b0 = __builtin_amdgcn_cvt_pk_fp8_f32(t[8], t[9], b0, false);
        b0 = __builtin_amdgcn_cvt_pk_fp8_f32(t[10], t[11], b0, true);
        b1 = __builtin_amdgcn_cvt_pk_fp8_f32(t[12], t[13], b1, false);
        b1 = __builtin_amdgcn_cvt_pk_fp8_f32(t[14], t[15], b1, true);
        int4 w = swap ? make_int4(b0, b1, a0, a1) : make_int4(a0, a1, b0, b1);
        *(int4*)(outb + g * 16) = w;
    }
}

// ---- Kernel B: fp8-K32 joint (R11 structure), gll staging, XCD-grouped mapping ------
// bx -> tile=(bx>>5)*8+(bx&7), quarter bh=(bx>>3)&3: a tile's 4 quarters share bx%8
// (same XCD L2), temporally adjacent. Wave wc: cols bh*256 + wc*64; acc[4][4]=64 AGPR.
__global__ __launch_bounds__(256, 3) void joint_mfma(const unsigned char* __restrict__ hG,
                                                     const unsigned char* __restrict__ Wf,
                                                     const float* __restrict__ bout,
                                                     const int* __restrict__ labels,
                                                     const int* __restrict__ pblank,
                                                     float* __restrict__ Spart,
                                                     float* __restrict__ blp,
                                                     float* __restrict__ llp) {
    __shared__ __align__(16) unsigned char hB[64 * 512];
    __shared__ float ps[4][64];

    int tid  = threadIdx.x;
    int bx   = blockIdx.x;
    int tile = (bx >> 5) * 8 + (bx & 7);
    int bh   = (bx >> 3) & 3;
    int c0   = tile * 64;
    int wc = tid >> 6, lane = tid & 63;
    int lg = lane >> 4, ln = lane & 15;

    // ---- stage hG tile -> LDS via global_load_lds (linear dest, 1KB/issue/wave) ----
    {
        const unsigned char* gsrc = hG + (size_t)tile * 32768 + wc * 8192 + lane * 16;
#pragma unroll
        for (int i = 0; i < 8; ++i)
            __builtin_amdgcn_global_load_lds((glb_uc*)(gsrc + i * 1024),
                                             (lds_uc*)(hB + wc * 8192 + i * 1024),
                                             16, 0, 0);
    }

    // frag-major Wf as longs: tile index bh*16 + wc*4 + ni (K32 layout)
    const long* wfbL = (const long*)Wf + (((bh << 4) + (wc << 2)) << 10) + lane;

    long bf[3][4];
    long af[2][4];
#pragma unroll
    for (int ni = 0; ni < 4; ++ni) bf[0][ni] = wfbL[ni * 1024];
#pragma unroll
    for (int ni = 0; ni < 4; ++ni) bf[1][ni] = wfbL[ni * 1024 + 64];

    __syncthreads();   // drains gll (vmcnt) + all waves staged

    f32x4 acc[4][4] = {};
#pragma unroll
    for (int mi = 0; mi < 4; ++mi)
        af[0][mi] = *(const long*)(hB + hb8((unsigned)(mi * 16 + ln), (unsigned)(lg * 8)));

#pragma unroll
    for (int kt = 0; kt < 16; ++kt) {
        const int cur3 = kt % 3;
        const int pf3  = (kt + 2) % 3;
        const int cur  = kt & 1, nxt = cur ^ 1;
#pragma unroll
        for (int ni = 0; ni < 4; ++ni) {
            if (kt < 14) bf[pf3][ni] = wfbL[ni * 1024 + (kt + 2) * 64];
            __builtin_amdgcn_s_setprio(1);
#pragma unroll
            for (int mi = 0; mi < 4; ++mi)
                acc[mi][ni] = __builtin_amdgcn_mfma_f32_16x16x32_fp8_fp8(
                    af[cur][mi], bf[cur3][ni], acc[mi][ni], 0, 0, 0);
            __builtin_amdgcn_s_setprio(0);
            if (ni == 1 && kt < 15) {
#pragma unroll
                for (int mi = 0; mi < 4; ++mi) {
                    unsigned m  = (unsigned)(mi * 16 + ln);
                    unsigned cb = (unsigned)((kt + 1) * 32 + lg * 8);
                    af[nxt][mi] = *(const long*)(hB + hb8(m, cb));
                }
            }
        }
    }

    // ---- epilogue: bias, partial exp-sum over this quarter's 256 cols, raw gather ----
    float bo[4];
#pragma unroll
    for (int ni = 0; ni < 4; ++ni) bo[ni] = bout[(bh << 8) + (wc << 6) + (ni << 4) + ln];
#pragma unroll
    for (int mi = 0; mi < 4; ++mi)
#pragma unroll
        for (int ni = 0; ni < 4; ++ni)
#pragma unroll
            for (int r = 0; r < 4; ++r) acc[mi][ni][r] += bo[ni];

#pragma unroll
    for (int mi = 0; mi < 4; ++mi) {
#pragma unroll
        for (int r = 0; r < 4; ++r) {
            float s = 0.f;
#pragma unroll
            for (int ni = 0; ni < 4; ++ni) s += __expf(acc[mi][ni][r]);
            s += __shfl_xor(s, 1);
            s += __shfl_xor(s, 2);
            s += __shfl_xor(s, 4);
            s += __shfl_xor(s, 8);
            if (ln == 0) ps[wc][mi * 16 + lg * 4 + r] = s;
        }
    }
    __syncthreads();
    if (tid < 64) {
        float S = ps[0][tid] + ps[1][tid] + ps[2][tid] + ps[3][tid];
        Spart[(size_t)bh * NCELL + c0 + tid] = S;
    }

    int blank = *pblank;
#pragma unroll
    for (int mi = 0; mi < 4; ++mi) {
#pragma unroll
        for (int r = 0; r < 4; ++r) {
            int row  = mi * 16 + lg * 4 + r;
            int cell = c0 + row;
            unsigned epRow = (unsigned)cell / 65u;
            int u = cell - (int)epRow * 65;
            int b = (int)(epRow >> 8);
            int lab = (u < U_) ? labels[(b << 6) + u] : -1;
#pragma unroll
            for (int ni = 0; ni < 4; ++ni) {
                int col = (bh << 8) + (wc << 6) + (ni << 4) + ln;
                float lgt = acc[mi][ni][r];
                if (col == blank) blp[cell] = lgt;                            // raw
                if (col == lab)   llp[(size_t)(((int)epRow << 6) + u)] = lgt; // raw
            }
        }
    }
}

// ---- Pass 2: lse = log(S0+S1+S2+S3); subtract from raw blank/label logits ----
__global__ __launch_bounds__(256) void pass2_kernel(const float* __restrict__ Spart,
                                                    float* __restrict__ blp,
                                                    float* __restrict__ llp) {
    int idx = blockIdx.x * 256 + threadIdx.x;
    if (idx >= NCELL) return;
    float lse = __logf(Spart[idx] + Spart[NCELL + idx] +
                       Spart[2 * NCELL + idx] + Spart[3 * NCELL + idx]);
    blp[idx] -= lse;
    unsigned epRow = (unsigned)idx / 65u;
    int u = idx - (int)epRow * 65;
    if (u < U_) llp[(size_t)((epRow << 6) + u)] -= lse;
}

// ------- Kernel C: alpha scan, log2-domain, DPP scans + prefetched loads ---------------
__global__ __launch_bounds__(512) void scan_kernel(const float* __restrict__ blp,
                                                   const float* __restrict__ llp,
                                                   const int* __restrict__ enc_lens,
                                                   const int* __restrict__ label_lens,
                                                   float* __restrict__ out) {
    __shared__ float lossArr[B_];
    const float K2  = 1.4426950408889634f;
    const float LN2 = 0.6931471805599453f;
    int tid  = threadIdx.x;
    int b    = tid >> 6;
    int lane = tid & 63;
    int el = enc_lens[b];
    int ll = label_lens[b];
    float alpha   = (lane == 0) ? 0.f : LOG0;
    float alpha64 = LOG0;
    const float* bb = &blp[(size_t)b * T_ * UP1];
    const float* lb = &llp[(size_t)b * T_ * U_];

    float bv_n   = bb[lane] * K2;
    float bv64_n = bb[64] * K2;
    float lv_n   = lb[lane] * K2;

    for (int t = 0; t < T_; ++t) {
        float bv = bv_n, bv64 = bv64_n, lv = lv_n;
        if (t + 1 < T_) {
            bv_n   = bb[(t + 1) * UP1 + lane] * K2;
            bv64_n = bb[(t + 1) * UP1 + 64] * K2;
            lv_n   = lb[(t + 1) * U_ + lane] * K2;
        }
        float P = wave_prefix_sum(lv);
        float L = dpps<0x111, 0xf>(P);
        float P15 = rdlane(P, 15), P31 = rdlane(P, 31), P47 = rdlane(P, 47);
        if (lane == 0)  L = 0.f;
        if (lane == 16) L = P15;
        if (lane == 32) L = P31;
        if (lane == 48) L = P47;
        float P63 = rdlane(P, 63);
        float x   = alpha + bv - L;
        float x64 = alpha64 + bv64 - P63;
        float M = fmaxf(wave_max_all(x), x64);
        float S = wave_prefix_sum(__builtin_amdgcn_exp2f(x - M));
        float S63 = rdlane(S, 63);
        float anew   = L + M + __builtin_amdgcn_logf(S);
        float anew64 = P63 + M +
                       __builtin_amdgcn_logf(S63 + __builtin_amdgcn_exp2f(x64 - M));
        if (t < el) {
            alpha   = anew;
            alpha64 = anew64;
        }
    }

    float term = bb[(el - 1) * UP1 + ll] * K2;
    int li = (ll < 64) ? ll : 63;
    float aU = __shfl(alpha, li);
    if (ll >= 64) aU = alpha64;
    if (lane == 0) lossArr[b] = -(aU + term) * LN2;
    __syncthreads();
    if (tid == 0) {
        float s = 0.f;
        for (int i = 0; i < B_; ++i) s += lossArr[i];
        out[0] = s / (float)B_;
    }
}

extern "C" void kernel_launch(void* const* d_in, const int* in_sizes, int n_in,
                              void* d_out, int out_size, void* d_ws, size_t ws_size,
                              hipStream_t stream) {
    (void)in_sizes; (void)n_in; (void)out_size; (void)ws_size;
    const float* enc        = (const float*)d_in[0];
    const float* pred       = (const float*)d_in[1];
    const float* W_enc      = (const float*)d_in[2];
    const float* W_pred     = (const float*)d_in[3];
    const float* b_joint    = (const float*)d_in[4];
    const float* W_out      = (const float*)d_in[5];
    const float* b_out      = (const float*)d_in[6];
    const int*   labels     = (const int*)d_in[7];
    const int*   enc_lens   = (const int*)d_in[8];
    const int*   label_lens = (const int*)d_in[9];
    const int*   blank_id   = (const int*)d_in[10];

    float* ep  = (float*)d_ws;                      // B*T*J   = 1,048,576 f
    float* pp  = ep  + (size_t)B_ * T_ * J_;        // B*65*J  =   266,240 f
    float* blp = pp  + (size_t)B_ * UP1 * J_;       // B*T*65  =   133,120 f
    float* llp = blp + (size_t)B_ * T_ * UP1;       // B*T*64  =   131,072 f
    unsigned char* Wf = (unsigned char*)(llp + (size_t)B_ * T_ * U_);  // 512KB frag fp8
    float* Spart = (float*)(Wf + (size_t)V_ * J_);  // 4 * NCELL f32
    unsigned char* hG = (unsigned char*)(Spart + (size_t)4 * NCELL);   // NCELL*512 fp8

    wt_kernel<<<dim3(V_ / 32, J_ / 32), dim3(256), 0, stream>>>(W_out, Wf);
    gemm_in<<<dim3((B_ * T_ + 63) / 64, J_ / 64), dim3(256), 0, stream>>>(
        enc, W_enc, b_joint, ep, B_ * T_);
    gemm_in<<<dim3((B_ * UP1 + 63) / 64, J_ / 64), dim3(256), 0, stream>>>(
        pred, W_pred, nullptr, pp, B_ * UP1);
    hgen_kernel<<<dim3(NCELL / 64), dim3(512), 0, stream>>>(ep, pp, hG);
    joint_mfma<<<dim3(NCELL / 64 * 4), dim3(256), 0, stream>>>(
        hG, Wf, b_out, labels, blank_id, Spart, blp, llp);
    pass2_kernel<<<dim3((NCELL + 255) / 256), dim3(256), 0, stream>>>(Spart, blp, llp);
    scan_kernel<<<dim3(1), dim3(512), 0, stream>>>(blp, llp, enc_lens, label_lens,
                                                   (float*)d_out);
}

// Round 14
// 344.259 us; speedup vs baseline: 2.3777x; 1.0458x over previous
//
#include <hip/hip_runtime.h>
#include <math.h>

#define B_   8
#define T_   256
#define U_   64
#define UP1  65
#define DE   640
#define J_   512
#define V_   1024
#define NCELL (B_ * T_ * UP1)
#define LOG0 -1e30f

typedef __attribute__((ext_vector_type(4))) float f32x4;

// ---------------- DPP wave64 scan/reduce helpers -------------------------------------
template<int CTRL, int RM>
__device__ __forceinline__ float dppz(float x) {
    return __builtin_bit_cast(float,
        __builtin_amdgcn_update_dpp(0, __builtin_bit_cast(int, x), CTRL, RM, 0xf, false));
}
template<int CTRL, int RM>
__device__ __forceinline__ float dpps(float x) {
    int xi = __builtin_bit_cast(int, x);
    return __builtin_bit_cast(float,
        __builtin_amdgcn_update_dpp(xi, xi, CTRL, RM, 0xf, false));
}
__device__ __forceinline__ float wave_prefix_sum(float v) {
    v += dppz<0x111, 0xf>(v);
    v += dppz<0x112, 0xf>(v);
    v += dppz<0x114, 0xf>(v);
    v += dppz<0x118, 0xf>(v);
    v += dppz<0x142, 0xa>(v);
    v += dppz<0x143, 0xc>(v);
    return v;
}
__device__ __forceinline__ float wave_max_all(float v) {
    v = fmaxf(v, dpps<0x111, 0xf>(v));
    v = fmaxf(v, dpps<0x112, 0xf>(v));
    v = fmaxf(v, dpps<0x114, 0xf>(v));
    v = fmaxf(v, dpps<0x118, 0xf>(v));
    v = fmaxf(v, dpps<0x142, 0xa>(v));
    v = fmaxf(v, dpps<0x143, 0xc>(v));
    return __builtin_bit_cast(float,
        __builtin_amdgcn_readlane(__builtin_bit_cast(int, v), 63));
}
__device__ __forceinline__ float rdlane(float v, int l) {
    return __builtin_bit_cast(float,
        __builtin_amdgcn_readlane(__builtin_bit_cast(int, v), l));
}

// LDS swizzle for fp8 hB: row m (512B rows), cb = column byte offset (8B granular).
__device__ __forceinline__ unsigned hb8(unsigned m, unsigned cb) {
    return m * 512u + (cb ^ ((m & 15u) << 3));
}

// ------- Kernel A: C[M x 512] = A[M x 640] * W[640 x 512] (+bias), 32x64 tiles --------
// 512 blocks for enc (2/CU) vs old 256 (1/CU): doubles TLP for the latency-bound GEMM.
__global__ __launch_bounds__(256) void gemm_in(const float* __restrict__ A,
                                               const float* __restrict__ W,
                                               const float* __restrict__ bias,
                                               float* __restrict__ C, int M) {
    __shared__ float As[16][32];
    __shared__ float Bs[16][64];
    int tid  = threadIdx.x;
    int row0 = blockIdx.x * 32;
    int col0 = blockIdx.y * 64;
    int tx = tid & 15, ty = tid >> 4;
    float acc[2][4] = {};
    int ar  = tid >> 3;        // 0..31: A-tile row
    int ak2 = (tid & 7) * 2;   // even k offset
    int bkr = tid >> 4;
    int bcq = tid & 15;
    for (int k0 = 0; k0 < DE; k0 += 16) {
        float2 av = make_float2(0.f, 0.f);
        int arow = row0 + ar;
        if (arow < M) av = *(const float2*)&A[arow * DE + k0 + ak2];
        As[ak2][ar]     = av.x;
        As[ak2 + 1][ar] = av.y;
        *(float4*)&Bs[bkr][bcq * 4] = *(const float4*)&W[(k0 + bkr) * J_ + col0 + bcq * 4];
        __syncthreads();
#pragma unroll
        for (int k = 0; k < 16; ++k) {
            float a0 = As[k][ty * 2], a1 = As[k][ty * 2 + 1];
            float4 b4 = *(const float4*)&Bs[k][tx * 4];
            float b[4] = {b4.x, b4.y, b4.z, b4.w};
#pragma unroll
            for (int j = 0; j < 4; ++j) {
                acc[0][j] += a0 * b[j];
                acc[1][j] += a1 * b[j];
            }
        }
        __syncthreads();
    }
#pragma unroll
    for (int i = 0; i < 2; ++i) {
        int row = row0 + ty * 2 + i;
        if (row >= M) continue;
#pragma unroll
        for (int j = 0; j < 4; ++j) {
            int col = col0 + tx * 4 + j;
            float v = acc[i][j];
            if (bias) v += bias[col];
            C[row * J_ + col] = v;
        }
    }
}

// ---- Kernel W: W_out[512][1024] -> fragment-major fp8(e4m3) Wf (round-6 K32 layout) --
__global__ __launch_bounds__(256) void wt_kernel(const float* __restrict__ W,
                                                 unsigned char* __restrict__ Wf) {
    __shared__ float tile[32][33];
    int tid = threadIdx.x;
    int tx = tid & 31, ty = tid >> 5;  // 32x8
    int v0 = blockIdx.x * 32, k0 = blockIdx.y * 32;
#pragma unroll
    for (int i = 0; i < 4; ++i)
        tile[ty + i * 8][tx] = W[(size_t)(k0 + ty + i * 8) * V_ + v0 + tx];
    __syncthreads();
    if (tid < 128) {
        int vl = tid >> 2, lg = tid & 3;
        int v  = v0 + vl;
        float x[8];
#pragma unroll
        for (int j = 0; j < 8; ++j) x[j] = tile[lg * 8 + j][vl];
        int lo = 0, hi = 0;
        lo = __builtin_amdgcn_cvt_pk_fp8_f32(x[0], x[1], lo, false);
        lo = __builtin_amdgcn_cvt_pk_fp8_f32(x[2], x[3], lo, true);
        hi = __builtin_amdgcn_cvt_pk_fp8_f32(x[4], x[5], hi, false);
        hi = __builtin_amdgcn_cvt_pk_fp8_f32(x[6], x[7], hi, true);
        int tl = v >> 4, ln = v & 15, kt = k0 >> 5;
        *(int2*)(Wf + tl * 8192 + kt * 512 + (lg * 16 + ln) * 8) = make_int2(lo, hi);
    }
}

// ---- Kernel H: h = tanh(ep+pp) fp8, pre-swizzled, OUTPUT-LINEAR (coalesced writes) ---
__global__ __launch_bounds__(512) void hgen_kernel(const float* __restrict__ ep,
                                                   const float* __restrict__ pp,
                                                   unsigned char* __restrict__ hG) {
    int tid  = threadIdx.x;
    int tile = blockIdx.x;
    unsigned char* outb = hG + (size_t)tile * 32768;
#pragma unroll
    for (int i = 0; i < 4; ++i) {
        int g   = tid + i * 512;
        int row = g >> 5;
        int lin9 = (g & 31) * 16;
        unsigned swz = ((unsigned)(row & 15)) << 3;
        int k0   = lin9 ^ (int)(swz & ~8u);
        int swap = row & 1;
        int cell = tile * 64 + row;
        unsigned epRow = (unsigned)cell / 65u;
        int u = cell - (int)epRow * 65;
        int b = (int)(epRow >> 8);
        const float* epr = ep + (size_t)epRow * J_ + k0;
        const float* ppr = pp + (size_t)(b * UP1 + u) * J_ + k0;
        float t[16];
#pragma unroll
        for (int q = 0; q < 4; ++q) {
            float4 e = *(const float4*)(epr + q * 4);
            float4 p = *(const float4*)(ppr + q * 4);
            float xs[4] = {e.x + p.x, e.y + p.y, e.z + p.z, e.w + p.w};
#pragma unroll
            for (int j = 0; j < 4; ++j) {
                float e2 = __expf(2.f * xs[j]);
                t[q * 4 + j] = 1.f - 2.f / (e2 + 1.f);
            }
        }
        int a0 = 0, a1 = 0, b0 = 0, b1 = 0;
        a0 = __builtin_amdgcn_cvt_pk_fp8_f32(t[0], t[1], a0, false);
        a0 = __builtin_amdgcn_cvt_pk_fp8_f32(t[2], t[3], a0, true);
        a1 = __builtin_amdgcn_cvt_pk_fp8_f32(t[4], t[5], a1, false);
        a1 = __builtin_amdgcn_cvt_pk_fp8_f32(t[6], t[7], a1, true);
        b0 = __builtin_amdgcn_cvt_pk_fp8_f32(t[8], t[9], b0, false);
        b0 = __builtin_amdgcn_cvt_pk_fp8_f32(t[10], t[11], b0, true);
        b1 = __builtin_amdgcn_cvt_pk_fp8_f32(t[12], t[13], b1, false);
        b1 = __builtin_amdgcn_cvt_pk_fp8_f32(t[14], t[15], b1, true);
        int4 w = swap ? make_int4(b0, b1, a0, a1) : make_int4(a0, a1, b0, b1);
        *(int4*)(outb + g * 16) = w;
    }
}

// ---- Kernel B: fp8-K32 joint, R11 reg staging (gll reverted), XCD-grouped mapping ---
// bx -> tile=(bx>>5)*8+(bx&7), quarter bh=(bx>>3)&3: tile's quarters share an XCD L2.
__global__ __launch_bounds__(256, 3) void joint_mfma(const unsigned char* __restrict__ hG,
                                                     const unsigned char* __restrict__ Wf,
                                                     const float* __restrict__ bout,
                                                     const int* __restrict__ labels,
                                                     const int* __restrict__ pblank,
                                                     float* __restrict__ Spart,
                                                     float* __restrict__ blp,
                                                     float* __restrict__ llp) {
    __shared__ __align__(16) unsigned char hB[64 * 512];
    __shared__ float ps[4][64];

    int tid  = threadIdx.x;
    int bx   = blockIdx.x;
    int tile = (bx >> 5) * 8 + (bx & 7);
    int bh   = (bx >> 3) & 3;
    int c0   = tile * 64;
    int wc = tid >> 6, lane = tid & 63;
    int lg = lane >> 4, ln = lane & 15;

    // frag-major Wf as longs: tile index bh*16 + wc*4 + ni (K32 layout)
    const long* wfbL = (const long*)Wf + (((bh << 4) + (wc << 2)) << 10) + lane;

    long bf[3][4];
    long af[2][4];

    // ---- stage: linear 32KB reg copy hG -> LDS, bf prologue overlapped (R11) ----
    {
        int4 v[8];
        const int4* g = (const int4*)(hG + (size_t)tile * 32768) + tid;
#pragma unroll
        for (int i = 0; i < 8; ++i) v[i] = g[i * 256];
#pragma unroll
        for (int ni = 0; ni < 4; ++ni) bf[0][ni] = wfbL[ni * 1024];
#pragma unroll
        for (int ni = 0; ni < 4; ++ni) bf[1][ni] = wfbL[ni * 1024 + 64];
#pragma unroll
        for (int i = 0; i < 8; ++i) ((int4*)hB)[tid + i * 256] = v[i];
    }
    __syncthreads();

    f32x4 acc[4][4] = {};
#pragma unroll
    for (int mi = 0; mi < 4; ++mi)
        af[0][mi] = *(const long*)(hB + hb8((unsigned)(mi * 16 + ln), (unsigned)(lg * 8)));

#pragma unroll
    for (int kt = 0; kt < 16; ++kt) {
        const int cur3 = kt % 3;
        const int pf3  = (kt + 2) % 3;
        const int cur  = kt & 1, nxt = cur ^ 1;
#pragma unroll
        for (int ni = 0; ni < 4; ++ni) {
            if (kt < 14) bf[pf3][ni] = wfbL[ni * 1024 + (kt + 2) * 64];
            __builtin_amdgcn_s_setprio(1);
#pragma unroll
            for (int mi = 0; mi < 4; ++mi)
                acc[mi][ni] = __builtin_amdgcn_mfma_f32_16x16x32_fp8_fp8(
                    af[cur][mi], bf[cur3][ni], acc[mi][ni], 0, 0, 0);
            __builtin_amdgcn_s_setprio(0);
            if (ni == 1 && kt < 15) {
#pragma unroll
                for (int mi = 0; mi < 4; ++mi) {
                    unsigned m  = (unsigned)(mi * 16 + ln);
                    unsigned cb = (unsigned)((kt + 1) * 32 + lg * 8);
                    af[nxt][mi] = *(const long*)(hB + hb8(m, cb));
                }
            }
        }
    }

    // ---- epilogue: bias, partial exp-sum over this quarter's 256 cols, raw gather ----
    float bo[4];
#pragma unroll
    for (int ni = 0; ni < 4; ++ni) bo[ni] = bout[(bh << 8) + (wc << 6) + (ni << 4) + ln];
#pragma unroll
    for (int mi = 0; mi < 4; ++mi)
#pragma unroll
        for (int ni = 0; ni < 4; ++ni)
#pragma unroll
            for (int r = 0; r < 4; ++r) acc[mi][ni][r] += bo[ni];

#pragma unroll
    for (int mi = 0; mi < 4; ++mi) {
#pragma unroll
        for (int r = 0; r < 4; ++r) {
            float s = 0.f;
#pragma unroll
            for (int ni = 0; ni < 4; ++ni) s += __expf(acc[mi][ni][r]);
            s += __shfl_xor(s, 1);
            s += __shfl_xor(s, 2);
            s += __shfl_xor(s, 4);
            s += __shfl_xor(s, 8);
            if (ln == 0) ps[wc][mi * 16 + lg * 4 + r] = s;
        }
    }
    __syncthreads();
    if (tid < 64) {
        float S = ps[0][tid] + ps[1][tid] + ps[2][tid] + ps[3][tid];
        Spart[(size_t)bh * NCELL + c0 + tid] = S;
    }

    int blank = *pblank;
#pragma unroll
    for (int mi = 0; mi < 4; ++mi) {
#pragma unroll
        for (int r = 0; r < 4; ++r) {
            int row  = mi * 16 + lg * 4 + r;
            int cell = c0 + row;
            unsigned epRow = (unsigned)cell / 65u;
            int u = cell - (int)epRow * 65;
            int b = (int)(epRow >> 8);
            int lab = (u < U_) ? labels[(b << 6) + u] : -1;
#pragma unroll
            for (int ni = 0; ni < 4; ++ni) {
                int col = (bh << 8) + (wc << 6) + (ni << 4) + ln;
                float lgt = acc[mi][ni][r];
                if (col == blank) blp[cell] = lgt;                            // raw
                if (col == lab)   llp[(size_t)(((int)epRow << 6) + u)] = lgt; // raw
            }
        }
    }
}

// ------- Kernel C: alpha scan with FUSED lse (pass2 folded into prefetch phase) -------
// blp/llp hold RAW logits; lse = log2(sum of 4 Spart partials), applied here.
__global__ __launch_bounds__(512) void scan_kernel(const float* __restrict__ blp,
                                                   const float* __restrict__ llp,
                                                   const float* __restrict__ Sp,
                                                   const int* __restrict__ enc_lens,
                                                   const int* __restrict__ label_lens,
                                                   float* __restrict__ out) {
    __shared__ float lossArr[B_];
    const float K2  = 1.4426950408889634f;
    const float LN2 = 0.6931471805599453f;
    int tid  = threadIdx.x;
    int b    = tid >> 6;
    int lane = tid & 63;
    int el = enc_lens[b];
    int ll = label_lens[b];
    float alpha   = (lane == 0) ? 0.f : LOG0;
    float alpha64 = LOG0;
    const float* bb = &blp[(size_t)b * T_ * UP1];
    const float* lb = &llp[(size_t)b * T_ * U_];
    const int cgb = b * (T_ * UP1);

    // prefetch+lse for t (log2 domain): bv = raw*K2 - log2(sum_q Sp[q][cell])
    float bv_n, bv64_n, lv_n;
    {
        int cg = cgb + lane;
        float Ss = Sp[cg] + Sp[NCELL + cg] + Sp[2 * NCELL + cg] + Sp[3 * NCELL + cg];
        float l2 = __builtin_amdgcn_logf(Ss);
        bv_n = bb[lane] * K2 - l2;
        lv_n = lb[lane] * K2 - l2;
        int c64 = cgb + 64;
        float S6 = Sp[c64] + Sp[NCELL + c64] + Sp[2 * NCELL + c64] + Sp[3 * NCELL + c64];
        bv64_n = bb[64] * K2 - __builtin_amdgcn_logf(S6);
    }

    for (int t = 0; t < T_; ++t) {
        float bv = bv_n, bv64 = bv64_n, lv = lv_n;
        if (t + 1 < T_) {
            int cg = cgb + (t + 1) * UP1 + lane;
            float Ss = Sp[cg] + Sp[NCELL + cg] + Sp[2 * NCELL + cg] + Sp[3 * NCELL + cg];
            float l2 = __builtin_amdgcn_logf(Ss);
            bv_n = bb[(t + 1) * UP1 + lane] * K2 - l2;
            lv_n = lb[(t + 1) * U_ + lane] * K2 - l2;
            int c64 = cgb + (t + 1) * UP1 + 64;
            float S6 = Sp[c64] + Sp[NCELL + c64] + Sp[2 * NCELL + c64] +
                       Sp[3 * NCELL + c64];
            bv64_n = bb[(t + 1) * UP1 + 64] * K2 - __builtin_amdgcn_logf(S6);
        }
        float P = wave_prefix_sum(lv);
        float L = dpps<0x111, 0xf>(P);
        float P15 = rdlane(P, 15), P31 = rdlane(P, 31), P47 = rdlane(P, 47);
        if (lane == 0)  L = 0.f;
        if (lane == 16) L = P15;
        if (lane == 32) L = P31;
        if (lane == 48) L = P47;
        float P63 = rdlane(P, 63);
        float x   = alpha + bv - L;
        float x64 = alpha64 + bv64 - P63;
        float M = fmaxf(wave_max_all(x), x64);
        float S = wave_prefix_sum(__builtin_amdgcn_exp2f(x - M));
        float S63 = rdlane(S, 63);
        float anew   = L + M + __builtin_amdgcn_logf(S);
        float anew64 = P63 + M +
                       __builtin_amdgcn_logf(S63 + __builtin_amdgcn_exp2f(x64 - M));
        if (t < el) {
            alpha   = anew;
            alpha64 = anew64;
        }
    }

    int ct = (el - 1) * UP1 + ll;
    int cg = cgb + ct;
    float St = Sp[cg] + Sp[NCELL + cg] + Sp[2 * NCELL + cg] + Sp[3 * NCELL + cg];
    float term = bb[ct] * K2 - __builtin_amdgcn_logf(St);
    int li = (ll < 64) ? ll : 63;
    float aU = __shfl(alpha, li);
    if (ll >= 64) aU = alpha64;
    if (lane == 0) lossArr[b] = -(aU + term) * LN2;
    __syncthreads();
    if (tid == 0) {
        float s = 0.f;
        for (int i = 0; i < B_; ++i) s += lossArr[i];
        out[0] = s / (float)B_;
    }
}

extern "C" void kernel_launch(void* const* d_in, const int* in_sizes, int n_in,
                              void* d_out, int out_size, void* d_ws, size_t ws_size,
                              hipStream_t stream) {
    (void)in_sizes; (void)n_in; (void)out_size; (void)ws_size;
    const float* enc        = (const float*)d_in[0];
    const float* pred       = (const float*)d_in[1];
    const float* W_enc      = (const float*)d_in[2];
    const float* W_pred     = (const float*)d_in[3];
    const float* b_joint    = (const float*)d_in[4];
    const float* W_out      = (const float*)d_in[5];
    const float* b_out      = (const float*)d_in[6];
    const int*   labels     = (const int*)d_in[7];
    const int*   enc_lens   = (const int*)d_in[8];
    const int*   label_lens = (const int*)d_in[9];
    const int*   blank_id   = (const int*)d_in[10];

    float* ep  = (float*)d_ws;                      // B*T*J   = 1,048,576 f
    float* pp  = ep  + (size_t)B_ * T_ * J_;        // B*65*J  =   266,240 f
    float* blp = pp  + (size_t)B_ * UP1 * J_;       // B*T*65  =   133,120 f
    float* llp = blp + (size_t)B_ * T_ * UP1;       // B*T*64  =   131,072 f
    unsigned char* Wf = (unsigned char*)(llp + (size_t)B_ * T_ * U_);  // 512KB frag fp8
    float* Spart = (float*)(Wf + (size_t)V_ * J_);  // 4 * NCELL f32
    unsigned char* hG = (unsigned char*)(Spart + (size_t)4 * NCELL);   // NCELL*512 fp8

    wt_kernel<<<dim3(V_ / 32, J_ / 32), dim3(256), 0, stream>>>(W_out, Wf);
    gemm_in<<<dim3((B_ * T_ + 31) / 32, J_ / 64), dim3(256), 0, stream>>>(
        enc, W_enc, b_joint, ep, B_ * T_);
    gemm_in<<<dim3((B_ * UP1 + 31) / 32, J_ / 64), dim3(256), 0, stream>>>(
        pred, W_pred, nullptr, pp, B_ * UP1);
    hgen_kernel<<<dim3(NCELL / 64), dim3(512), 0, stream>>>(ep, pp, hG);
    joint_mfma<<<dim3(NCELL / 64 * 4), dim3(256), 0, stream>>>(
        hG, Wf, b_out, labels, blank_id, Spart, blp, llp);
    scan_kernel<<<dim3(1), dim3(512), 0, stream>>>(blp, llp, Spart, enc_lens,
                                                   label_lens, (float*)d_out);
}